// Round 8
// baseline (323.886 us; speedup 1.0000x reference)
//
#include <hip/hip_runtime.h>
#include <hip/hip_bf16.h>
#include <cstdint>
#include <cstddef>

#define BSZ 8
#define NN 2048
#define HH 512
#define MROWS (BSZ * NN)   // 16384
#define LOG2E 1.44269504088896f

typedef __attribute__((ext_vector_type(4))) float f32x4;
typedef __attribute__((ext_vector_type(8))) short short8;
typedef __attribute__((ext_vector_type(4))) unsigned short us4;
typedef __attribute__((ext_vector_type(4))) uint32_t u32x4;

#if __has_builtin(__builtin_amdgcn_exp2f)
#define EXP2(x) __builtin_amdgcn_exp2f(x)
#else
#define EXP2(x) __expf((x) * 0.69314718056f)
#endif

static __device__ __forceinline__ unsigned short f2bf(float f) {
    uint32_t u = __builtin_bit_cast(uint32_t, f);
    u += 0x7fffu + ((u >> 16) & 1u);
    return (unsigned short)(u >> 16);
}

static __device__ __forceinline__ void async16(const unsigned short* g, unsigned short* l) {
    __builtin_amdgcn_global_load_lds(
        (const __attribute__((address_space(1))) void*)g,
        (__attribute__((address_space(3))) void*)l, 16, 0, 0);
}

// =====================================================================================
// K0 prep: blocks [0,2048): feats -> bf16 (4 f32x4/thread)
//          blocks [2048,2112): fc_w -> bf16
// =====================================================================================
__global__ __launch_bounds__(256) void prep_kernel(
    const float* __restrict__ feats, const float* __restrict__ fc_w,
    unsigned short* __restrict__ feats_bf, unsigned short* __restrict__ fcw_bf) {
    const int bid = blockIdx.x;
    const int tid = threadIdx.x;
    if (bid < 2048) {
        const int base = bid * 1024 + tid;
#pragma unroll
        for (int j = 0; j < 4; ++j) {
            const int i = base + j * 256;
            f32x4 v = ((const f32x4*)feats)[i];
            us4 o;
#pragma unroll
            for (int c = 0; c < 4; ++c) o[c] = f2bf(v[c]);
            ((us4*)feats_bf)[i] = o;
        }
    } else {
        const int base = (bid - 2048) * 1024 + tid;
#pragma unroll
        for (int j = 0; j < 4; ++j) {
            const int i = base + j * 256;
            f32x4 v = ((const f32x4*)fc_w)[i];
            us4 o;
#pragma unroll
            for (int c = 0; c < 4; ++c) o[c] = f2bf(v[c]);
            ((us4*)fcw_bf)[i] = o;
        }
    }
}

// =====================================================================================
// K2: blocks [0,512): gemm_fp via async16 bf16 staging (m97 pattern):
//       fpT[b][o][i] = sum_h feats[b,i,h]*fc_w[o,h] + fc_b[o]   (bf16 store, transposed)
//       + epilogue q/k partials  qpart/kpart[o_tile][row].
//     blocks [512,2560): adj -> bitmask, 8 rows per block.
// =====================================================================================
__global__ __launch_bounds__(256) void k2_kernel(
    const unsigned short* __restrict__ A, const unsigned short* __restrict__ Bt,
    const float* __restrict__ fc_b, const float* __restrict__ q_w,
    const float* __restrict__ k_w, const float* __restrict__ adj,
    unsigned short* __restrict__ fpT, unsigned char* __restrict__ maskb,
    float* __restrict__ qpart, float* __restrict__ kpart) {
    const int bid = blockIdx.x;
    const int tid = threadIdx.x;
    if (bid < 512) {
        __shared__ alignas(16) unsigned short As[128 * 32];
        __shared__ alignas(16) unsigned short Bs[128 * 32];
        __shared__ float qred[2][128], kred[2][128];
        const int wave = tid >> 6, lane = tid & 63;
        const int wi = wave >> 1, wj = wave & 1;
        const int n0 = (bid & 3) * 128;     // o tile
        const int i0 = (bid >> 2) * 128;    // flat row tile
        const int K = HH;
        const int lrow = lane >> 2;         // 0..15
        const int lseg = (lane & 3) * 8;    // 0,8,16,24
        const int fro = (lane & 15) * 32 + (lane >> 4) * 8;
        f32x4 acc[4][4];
#pragma unroll
        for (int a = 0; a < 4; ++a)
#pragma unroll
            for (int c = 0; c < 4; ++c) acc[a][c] = (f32x4)(0.f);

        for (int k0 = 0; k0 < K; k0 += 32) {
            __syncthreads();
            {
                const int c0 = wave * 2;
                const unsigned short* ga = A + (size_t)(i0 + c0 * 16 + lrow) * K + k0 + lseg;
                async16(ga, &As[(c0 * 16) * 32]);
                async16(ga + (size_t)16 * K, &As[(c0 * 16 + 16) * 32]);
                const unsigned short* gb = Bt + (size_t)(n0 + c0 * 16 + lrow) * K + k0 + lseg;
                async16(gb, &Bs[(c0 * 16) * 32]);
                async16(gb + (size_t)16 * K, &Bs[(c0 * 16 + 16) * 32]);
            }
            __syncthreads();
            short8 af[4], bf[4];
#pragma unroll
            for (int t = 0; t < 4; ++t) af[t] = *(const short8*)&As[(wi * 64 + t * 16) * 32 + fro];
#pragma unroll
            for (int t = 0; t < 4; ++t) bf[t] = *(const short8*)&Bs[(wj * 64 + t * 16) * 32 + fro];
#pragma unroll
            for (int it = 0; it < 4; ++it)
#pragma unroll
                for (int jt = 0; jt < 4; ++jt)
                    acc[it][jt] = __builtin_amdgcn_mfma_f32_16x16x32_bf16(af[it], bf[jt], acc[it][jt], 0, 0, 0);
        }

        int colv[4]; float cbv[4], qwv[4], kwv[4];
#pragma unroll
        for (int jt = 0; jt < 4; ++jt) {
            colv[jt] = n0 + wj * 64 + jt * 16 + (lane & 15);
            cbv[jt] = fc_b[colv[jt]];
            qwv[jt] = q_w[colv[jt]];
            kwv[jt] = k_w[colv[jt]];
        }
        const int b = i0 >> 11;
        const int il = i0 & 2047;
#pragma unroll
        for (int jt = 0; jt < 4; ++jt) {
#pragma unroll
            for (int it = 0; it < 4; ++it) {
                const int rb = wi * 64 + it * 16 + ((lane >> 4) << 2);
                us4 o;
#pragma unroll
                for (int r = 0; r < 4; ++r) o[r] = f2bf(acc[it][jt][r] + cbv[jt]);
                *(us4*)(fpT + ((size_t)b * HH + colv[jt]) * NN + il + rb) = o;
            }
        }
        // q/k partials over this block's 128 o-cols
#pragma unroll
        for (int it = 0; it < 4; ++it) {
#pragma unroll
            for (int r = 0; r < 4; ++r) {
                float pq = 0.f, pk = 0.f;
#pragma unroll
                for (int jt = 0; jt < 4; ++jt) {
                    float v = acc[it][jt][r] + cbv[jt];
                    pq += v * qwv[jt];
                    pk += v * kwv[jt];
                }
                for (int off = 1; off < 16; off <<= 1) {
                    pq += __shfl_xor(pq, off, 64);
                    pk += __shfl_xor(pk, off, 64);
                }
                if ((lane & 15) == 0) {
                    const int rr = wi * 64 + it * 16 + ((lane >> 4) << 2) + r;
                    qred[wj][rr] = pq;
                    kred[wj][rr] = pk;
                }
            }
        }
        __syncthreads();
        if (tid < 128) {
            const size_t o = (size_t)(n0 >> 7) * MROWS + i0 + tid;
            qpart[o] = qred[0][tid] + qred[1][tid];
            kpart[o] = kred[0][tid] + kred[1][tid];
        }
    } else {
        // ---- adj -> bitmask: 8 rows per block ----
        const int a = bid - 512;             // 0..2047
        const int wave = tid >> 6, lane = tid & 63;
#pragma unroll
        for (int s = 0; s < 2; ++s) {
            const int row = a * 8 + s * 4 + wave;
            const float* ar = adj + (size_t)row * NN;
#pragma unroll
            for (int p = 0; p < 4; ++p) {
                f32x4 v0 = *(const f32x4*)&ar[p * 512 + lane * 8];
                f32x4 v1 = *(const f32x4*)&ar[p * 512 + lane * 8 + 4];
                float fb = v0[0] + 2.f * v0[1] + 4.f * v0[2] + 8.f * v0[3]
                         + 16.f * v1[0] + 32.f * v1[1] + 64.f * v1[2] + 128.f * v1[3];
                maskb[(size_t)row * 256 + p * 64 + lane] = (unsigned char)(unsigned int)fb;
            }
        }
    }
}

// =====================================================================================
// K3: fused W-build + PV GEMM. M=64 rows x N=256 h-cols per block, BK=32.
// Transform: exp2 with prescaled q/k, lrelu = fmax(s, .01s), pack via +0x8000 + perm.
// =====================================================================================
__global__ __launch_bounds__(256) void fused_pv_kernel(
    const unsigned short* __restrict__ fpT, const unsigned char* __restrict__ maskb,
    const float* __restrict__ qpart, const float* __restrict__ kpart,
    const float* __restrict__ q_b, const float* __restrict__ k_b,
    const float* __restrict__ feats, float* __restrict__ out) {
    __shared__ alignas(16) unsigned short As[64 * 32];    // 4 KB
    __shared__ alignas(16) unsigned short Bs[256 * 32];   // 16 KB
    __shared__ float kLDS[NN];                            // 8 KB
    __shared__ float qLDS[64];
    __shared__ float zfl[256];
    __shared__ float rzl[64];
    const int tid = threadIdx.x;
    const int wave = tid >> 6, lane = tid & 63;
    const int wi = wave >> 1, wj = wave & 1;
    const int bid = blockIdx.x;
    const int b = bid & 7;               // batch == XCD slot for fpT L2 locality
    const int t6 = bid >> 3;             // 0..63
    const int i0 = (t6 >> 1) * 64;       // row tile within batch
    const int n0 = (t6 & 1) * 256;       // h half
    const size_t rowbase = (size_t)b * NN + i0;

    // prologue: prescaled k (all 2048) and q (64 rows) into LDS
    {
        const float kb = k_b[0], qb = q_b[0];
#pragma unroll
        for (int s = 0; s < 8; ++s) {
            const int j = s * 256 + tid;
            const size_t gj = (size_t)b * NN + j;
            kLDS[j] = (kpart[gj] + kpart[MROWS + gj] + kpart[2 * MROWS + gj]
                     + kpart[3 * MROWS + gj] + kb) * LOG2E;
        }
        if (tid < 64) {
            const size_t gi = rowbase + tid;
            qLDS[tid] = (qpart[gi] + qpart[MROWS + gi] + qpart[2 * MROWS + gi]
                       + qpart[3 * MROWS + gi] + qb) * LOG2E;
        }
    }
    __syncthreads();

    const int r0 = tid >> 2;            // 0..63: W row handled by this thread
    const int c8 = (tid & 3) * 8;       // 8 consecutive K cols
    const float qi = qLDS[r0];
    float z = 0.f;

    const unsigned short* Bt = fpT + (size_t)b * HH * NN;
    const uint32_t* mk = (const uint32_t*)maskb;
    const size_t mrow = (rowbase + r0) * 64;
    const int lrow = lane >> 2, lseg = (lane & 3) * 8;
    const int fro = (lane & 15) * 32 + (lane >> 4) * 8;

    f32x4 acc[2][8];
#pragma unroll
    for (int a = 0; a < 2; ++a)
#pragma unroll
        for (int c = 0; c < 8; ++c) acc[a][c] = (f32x4)(0.f);

    uint32_t mcur = mk[mrow];           // bits for k0 = 0
    for (int k0 = 0; k0 < NN; k0 += 32) {
        __syncthreads();
        // stage B: each wave stages 64 rows (4 chunks of 16)
        {
            const int rbase = wave * 64;
            const unsigned short* gb = Bt + (size_t)(n0 + rbase + lrow) * NN + k0 + lseg;
            async16(gb, &Bs[rbase * 32]);
            async16(gb + (size_t)16 * NN, &Bs[(rbase + 16) * 32]);
            async16(gb + (size_t)32 * NN, &Bs[(rbase + 32) * 32]);
            async16(gb + (size_t)48 * NN, &Bs[(rbase + 48) * 32]);
        }
        uint32_t mnext = 0;
        if (k0 + 32 < NN) mnext = mk[mrow + ((k0 + 32) >> 5)];
        // transform: 8 W elements (1 row x 8 cols) -> As
        const f32x4 kv0 = *(const f32x4*)&kLDS[k0 + c8];
        const f32x4 kv1 = *(const f32x4*)&kLDS[k0 + c8 + 4];
        const uint32_t byte8 = (mcur >> c8) & 0xffu;
        float wv[8];
#pragma unroll
        for (int c = 0; c < 8; ++c) {
            float s = qi + (c < 4 ? kv0[c] : kv1[c - 4]);
            s = fmaxf(s, 0.01f * s);
            float e = EXP2(s);
            wv[c] = ((byte8 >> c) & 1u) ? e : 0.f;
            z += wv[c];
        }
        u32x4 pk;
#pragma unroll
        for (int p = 0; p < 4; ++p) {
            uint32_t lo = __builtin_bit_cast(uint32_t, wv[2 * p]) + 0x8000u;
            uint32_t hi = __builtin_bit_cast(uint32_t, wv[2 * p + 1]) + 0x8000u;
            pk[p] = __builtin_amdgcn_perm(hi, lo, 0x07060302u);
        }
        *(u32x4*)&As[r0 * 32 + c8] = pk;   // byte addr = tid*16, linear, conflict-free
        __syncthreads();
        short8 af[2], bf[8];
#pragma unroll
        for (int t = 0; t < 2; ++t) af[t] = *(const short8*)&As[(wi * 32 + t * 16) * 32 + fro];
#pragma unroll
        for (int t = 0; t < 8; ++t) bf[t] = *(const short8*)&Bs[(wj * 128 + t * 16) * 32 + fro];
#pragma unroll
        for (int it = 0; it < 2; ++it)
#pragma unroll
            for (int jt = 0; jt < 8; ++jt)
                acc[it][jt] = __builtin_amdgcn_mfma_f32_16x16x32_bf16(af[it], bf[jt], acc[it][jt], 0, 0, 0);
        mcur = mnext;
    }

    // Z reduction: 4 threads per row
    zfl[tid] = z;
    __syncthreads();
    if (tid < 64) {
        const float* zp = &zfl[tid * 4];
        rzl[tid] = 1.0f / (zp[0] + zp[1] + zp[2] + zp[3]);
    }
    __syncthreads();

    // epilogue: scale by 1/Z, add residual, plain fp32 stores
#pragma unroll
    for (int it = 0; it < 2; ++it) {
        const int rb = wi * 32 + it * 16 + ((lane >> 4) << 2);
        float rv[4];
#pragma unroll
        for (int r = 0; r < 4; ++r) rv[r] = rzl[rb + r];
#pragma unroll
        for (int jt = 0; jt < 8; ++jt) {
            const int col = n0 + wj * 128 + jt * 16 + (lane & 15);
#pragma unroll
            for (int r = 0; r < 4; ++r) {
                const size_t idx = (rowbase + rb + r) * HH + col;
                out[idx] = acc[it][jt][r] * rv[r] + feats[idx];
            }
        }
    }
}

extern "C" void kernel_launch(void* const* d_in, const int* in_sizes, int n_in,
                              void* d_out, int out_size, void* d_ws, size_t ws_size,
                              hipStream_t stream) {
    const float* feats = (const float*)d_in[0];
    const float* adj   = (const float*)d_in[1];
    const float* fc_w  = (const float*)d_in[2];
    const float* fc_b  = (const float*)d_in[3];
    const float* q_w   = (const float*)d_in[4];
    const float* q_b   = (const float*)d_in[5];
    const float* k_w   = (const float*)d_in[6];
    const float* k_b   = (const float*)d_in[7];
    float* out = (float*)d_out;

    char* w = (char*)d_ws;
    auto alloc = [&](size_t bytes) {
        char* p = w;
        w += (bytes + 255) & ~(size_t)255;
        return p;
    };
    unsigned short* feats_bf = (unsigned short*)alloc((size_t)BSZ * NN * HH * 2); // 16.8 MB
    unsigned short* fcw_bf   = (unsigned short*)alloc((size_t)HH * HH * 2);       // 0.5 MB
    unsigned short* fpT   = (unsigned short*)alloc((size_t)BSZ * HH * NN * 2);    // 16.8 MB
    unsigned char*  maskb = (unsigned char*)alloc((size_t)MROWS * 256);           // 4.2 MB
    float* qpart = (float*)alloc((size_t)4 * MROWS * 4);                          // 256 KB
    float* kpart = (float*)alloc((size_t)4 * MROWS * 4);                          // 256 KB

    prep_kernel<<<2112, 256, 0, stream>>>(feats, fc_w, feats_bf, fcw_bf);
    k2_kernel<<<512 + 2048, 256, 0, stream>>>(feats_bf, fcw_bf, fc_b, q_w, k_w, adj,
                                              fpT, maskb, qpart, kpart);
    fused_pv_kernel<<<512, 256, 0, stream>>>(
        fpT, maskb, qpart, kpart, q_b, k_b, feats, out);
}

// Round 9
// 313.988 us; speedup vs baseline: 1.0315x; 1.0315x over previous
//
#include <hip/hip_runtime.h>
#include <hip/hip_bf16.h>
#include <cstdint>
#include <cstddef>

#define BSZ 8
#define NN 2048
#define HH 512
#define MROWS (BSZ * NN)   // 16384
#define LOG2E 1.44269504088896f

typedef __attribute__((ext_vector_type(4))) float f32x4;
typedef __attribute__((ext_vector_type(8))) short short8;
typedef __attribute__((ext_vector_type(4))) unsigned short us4;
typedef __attribute__((ext_vector_type(4))) uint32_t u32x4;

#if __has_builtin(__builtin_amdgcn_exp2f)
#define EXP2(x) __builtin_amdgcn_exp2f(x)
#else
#define EXP2(x) __expf((x) * 0.69314718056f)
#endif

static __device__ __forceinline__ unsigned short f2bf(float f) {
    uint32_t u = __builtin_bit_cast(uint32_t, f);
    u += 0x7fffu + ((u >> 16) & 1u);
    return (unsigned short)(u >> 16);
}

static __device__ __forceinline__ void async16(const unsigned short* g, unsigned short* l) {
    __builtin_amdgcn_global_load_lds(
        (const __attribute__((address_space(1))) void*)g,
        (__attribute__((address_space(3))) void*)l, 16, 0, 0);
}

// =====================================================================================
// K0 prep: blocks [0,2048): feats -> bf16 (4 f32x4/thread)
//          blocks [2048,2112): fc_w -> bf16
// =====================================================================================
__global__ __launch_bounds__(256) void prep_kernel(
    const float* __restrict__ feats, const float* __restrict__ fc_w,
    unsigned short* __restrict__ feats_bf, unsigned short* __restrict__ fcw_bf) {
    const int bid = blockIdx.x;
    const int tid = threadIdx.x;
    if (bid < 2048) {
        const int base = bid * 1024 + tid;
#pragma unroll
        for (int j = 0; j < 4; ++j) {
            const int i = base + j * 256;
            f32x4 v = ((const f32x4*)feats)[i];
            us4 o;
#pragma unroll
            for (int c = 0; c < 4; ++c) o[c] = f2bf(v[c]);
            ((us4*)feats_bf)[i] = o;
        }
    } else {
        const int base = (bid - 2048) * 1024 + tid;
#pragma unroll
        for (int j = 0; j < 4; ++j) {
            const int i = base + j * 256;
            f32x4 v = ((const f32x4*)fc_w)[i];
            us4 o;
#pragma unroll
            for (int c = 0; c < 4; ++c) o[c] = f2bf(v[c]);
            ((us4*)fcw_bf)[i] = o;
        }
    }
}

// =====================================================================================
// K2: blocks [0,512): gemm_fp via async16 bf16 staging (m97 pattern) + q/k partials.
//     blocks [512,2560): adj -> bitmask.
// =====================================================================================
__global__ __launch_bounds__(256) void k2_kernel(
    const unsigned short* __restrict__ A, const unsigned short* __restrict__ Bt,
    const float* __restrict__ fc_b, const float* __restrict__ q_w,
    const float* __restrict__ k_w, const float* __restrict__ adj,
    unsigned short* __restrict__ fpT, unsigned char* __restrict__ maskb,
    float* __restrict__ qpart, float* __restrict__ kpart) {
    const int bid = blockIdx.x;
    const int tid = threadIdx.x;
    if (bid < 512) {
        __shared__ alignas(16) unsigned short As[128 * 32];
        __shared__ alignas(16) unsigned short Bs[128 * 32];
        __shared__ float qred[2][128], kred[2][128];
        const int wave = tid >> 6, lane = tid & 63;
        const int wi = wave >> 1, wj = wave & 1;
        const int n0 = (bid & 3) * 128;     // o tile
        const int i0 = (bid >> 2) * 128;    // flat row tile
        const int K = HH;
        const int lrow = lane >> 2;         // 0..15
        const int lseg = (lane & 3) * 8;    // 0,8,16,24
        const int fro = (lane & 15) * 32 + (lane >> 4) * 8;
        f32x4 acc[4][4];
#pragma unroll
        for (int a = 0; a < 4; ++a)
#pragma unroll
            for (int c = 0; c < 4; ++c) acc[a][c] = (f32x4)(0.f);

        for (int k0 = 0; k0 < K; k0 += 32) {
            __syncthreads();
            {
                const int c0 = wave * 2;
                const unsigned short* ga = A + (size_t)(i0 + c0 * 16 + lrow) * K + k0 + lseg;
                async16(ga, &As[(c0 * 16) * 32]);
                async16(ga + (size_t)16 * K, &As[(c0 * 16 + 16) * 32]);
                const unsigned short* gb = Bt + (size_t)(n0 + c0 * 16 + lrow) * K + k0 + lseg;
                async16(gb, &Bs[(c0 * 16) * 32]);
                async16(gb + (size_t)16 * K, &Bs[(c0 * 16 + 16) * 32]);
            }
            __syncthreads();
            short8 af[4], bf[4];
#pragma unroll
            for (int t = 0; t < 4; ++t) af[t] = *(const short8*)&As[(wi * 64 + t * 16) * 32 + fro];
#pragma unroll
            for (int t = 0; t < 4; ++t) bf[t] = *(const short8*)&Bs[(wj * 64 + t * 16) * 32 + fro];
#pragma unroll
            for (int it = 0; it < 4; ++it)
#pragma unroll
                for (int jt = 0; jt < 4; ++jt)
                    acc[it][jt] = __builtin_amdgcn_mfma_f32_16x16x32_bf16(af[it], bf[jt], acc[it][jt], 0, 0, 0);
        }

        int colv[4]; float cbv[4], qwv[4], kwv[4];
#pragma unroll
        for (int jt = 0; jt < 4; ++jt) {
            colv[jt] = n0 + wj * 64 + jt * 16 + (lane & 15);
            cbv[jt] = fc_b[colv[jt]];
            qwv[jt] = q_w[colv[jt]];
            kwv[jt] = k_w[colv[jt]];
        }
        const int b = i0 >> 11;
        const int il = i0 & 2047;
#pragma unroll
        for (int jt = 0; jt < 4; ++jt) {
#pragma unroll
            for (int it = 0; it < 4; ++it) {
                const int rb = wi * 64 + it * 16 + ((lane >> 4) << 2);
                us4 o;
#pragma unroll
                for (int r = 0; r < 4; ++r) o[r] = f2bf(acc[it][jt][r] + cbv[jt]);
                *(us4*)(fpT + ((size_t)b * HH + colv[jt]) * NN + il + rb) = o;
            }
        }
        // q/k partials over this block's 128 o-cols
#pragma unroll
        for (int it = 0; it < 4; ++it) {
#pragma unroll
            for (int r = 0; r < 4; ++r) {
                float pq = 0.f, pk = 0.f;
#pragma unroll
                for (int jt = 0; jt < 4; ++jt) {
                    float v = acc[it][jt][r] + cbv[jt];
                    pq += v * qwv[jt];
                    pk += v * kwv[jt];
                }
                for (int off = 1; off < 16; off <<= 1) {
                    pq += __shfl_xor(pq, off, 64);
                    pk += __shfl_xor(pk, off, 64);
                }
                if ((lane & 15) == 0) {
                    const int rr = wi * 64 + it * 16 + ((lane >> 4) << 2) + r;
                    qred[wj][rr] = pq;
                    kred[wj][rr] = pk;
                }
            }
        }
        __syncthreads();
        if (tid < 128) {
            const size_t o = (size_t)(n0 >> 7) * MROWS + i0 + tid;
            qpart[o] = qred[0][tid] + qred[1][tid];
            kpart[o] = kred[0][tid] + kred[1][tid];
        }
    } else {
        // ---- adj -> bitmask: 8 rows per block ----
        const int a = bid - 512;             // 0..2047
        const int wave = tid >> 6, lane = tid & 63;
#pragma unroll
        for (int s = 0; s < 2; ++s) {
            const int row = a * 8 + s * 4 + wave;
            const float* ar = adj + (size_t)row * NN;
#pragma unroll
            for (int p = 0; p < 4; ++p) {
                f32x4 v0 = *(const f32x4*)&ar[p * 512 + lane * 8];
                f32x4 v1 = *(const f32x4*)&ar[p * 512 + lane * 8 + 4];
                float fb = v0[0] + 2.f * v0[1] + 4.f * v0[2] + 8.f * v0[3]
                         + 16.f * v1[0] + 32.f * v1[1] + 64.f * v1[2] + 128.f * v1[3];
                maskb[(size_t)row * 256 + p * 64 + lane] = (unsigned char)(unsigned int)fb;
            }
        }
    }
}

// =====================================================================================
// K3 v3: fused W-build + PV GEMM, double-buffered (1 barrier/iter), Z via ones-MFMA.
// M=64 x N=256 per block, BK=32. Transform packs bf16 by truncation (perm only).
// =====================================================================================
__global__ __launch_bounds__(256) void fused_pv_kernel(
    const unsigned short* __restrict__ fpT, const unsigned char* __restrict__ maskb,
    const float* __restrict__ qpart, const float* __restrict__ kpart,
    const float* __restrict__ q_b, const float* __restrict__ k_b,
    const float* __restrict__ feats, float* __restrict__ out) {
    __shared__ alignas(16) unsigned short As[2][64 * 32];    // 8 KB
    __shared__ alignas(16) unsigned short Bs[2][256 * 32];   // 32 KB
    __shared__ float kLDS[NN];                               // 8 KB
    __shared__ float qLDS[64];
    __shared__ float rzl[64];
    const int tid = threadIdx.x;
    const int wave = tid >> 6, lane = tid & 63;
    const int wi = wave >> 1, wj = wave & 1;
    const int bid = blockIdx.x;
    const int b = bid & 7;               // batch == XCD slot for fpT L2 locality
    const int t6 = bid >> 3;             // 0..63
    const int i0 = (t6 >> 1) * 64;       // row tile within batch
    const int n0 = (t6 & 1) * 256;       // h half
    const size_t rowbase = (size_t)b * NN + i0;

    // prologue: prescaled k (all 2048) and q (64 rows) into LDS
    {
        const float kb = k_b[0], qb = q_b[0];
#pragma unroll
        for (int s = 0; s < 8; ++s) {
            const int j = s * 256 + tid;
            const size_t gj = (size_t)b * NN + j;
            kLDS[j] = (kpart[gj] + kpart[MROWS + gj] + kpart[2 * MROWS + gj]
                     + kpart[3 * MROWS + gj] + kb) * LOG2E;
        }
        if (tid < 64) {
            const size_t gi = rowbase + tid;
            qLDS[tid] = (qpart[gi] + qpart[MROWS + gi] + qpart[2 * MROWS + gi]
                       + qpart[3 * MROWS + gi] + qb) * LOG2E;
        }
    }
    __syncthreads();

    const int r0 = tid >> 2;            // 0..63: W row handled by this thread
    const int c8 = (tid & 3) * 8;       // 8 consecutive K cols
    const float qi = qLDS[r0];

    const unsigned short* Bt = fpT + (size_t)b * HH * NN;
    const uint32_t* mk = (const uint32_t*)maskb;
    const size_t mrow = (rowbase + r0) * 64;
    const int lrow = lane >> 2, lseg = (lane & 3) * 8;
    const int fro = (lane & 15) * 32 + (lane >> 4) * 8;

    auto stageB = [&](int buf, int k0) {
        const int rbase = wave * 64;
        const unsigned short* gb = Bt + (size_t)(n0 + rbase + lrow) * NN + k0 + lseg;
        async16(gb, &Bs[buf][rbase * 32]);
        async16(gb + (size_t)16 * NN, &Bs[buf][(rbase + 16) * 32]);
        async16(gb + (size_t)32 * NN, &Bs[buf][(rbase + 32) * 32]);
        async16(gb + (size_t)48 * NN, &Bs[buf][(rbase + 48) * 32]);
    };
    auto transform = [&](int buf, int k0, uint32_t mbits) {
        const f32x4 kv0 = *(const f32x4*)&kLDS[k0 + c8];
        const f32x4 kv1 = *(const f32x4*)&kLDS[k0 + c8 + 4];
        const uint32_t byte8 = (mbits >> c8) & 0xffu;
        float wv[8];
#pragma unroll
        for (int c = 0; c < 8; ++c) {
            float s = qi + (c < 4 ? kv0[c] : kv1[c - 4]);
            s = fmaxf(s, 0.01f * s);
            const float e = EXP2(s);
            wv[c] = ((byte8 >> c) & 1u) ? e : 0.f;
        }
        u32x4 pk;
#pragma unroll
        for (int p = 0; p < 4; ++p) {
            const uint32_t lo = __builtin_bit_cast(uint32_t, wv[2 * p]);
            const uint32_t hi = __builtin_bit_cast(uint32_t, wv[2 * p + 1]);
            pk[p] = __builtin_amdgcn_perm(hi, lo, 0x07060302u);  // truncate-pack 2x bf16
        }
        *(u32x4*)&As[buf][r0 * 32 + c8] = pk;  // byte addr = tid*16, linear, conflict-free
    };

    f32x4 acc[2][8];
#pragma unroll
    for (int a = 0; a < 2; ++a)
#pragma unroll
        for (int c = 0; c < 8; ++c) acc[a][c] = (f32x4)(0.f);
    f32x4 acc_z[2] = {(f32x4)(0.f), (f32x4)(0.f)};
    short8 ones;
#pragma unroll
    for (int j = 0; j < 8; ++j) ones[j] = (short)0x3F80;   // bf16 1.0

    // prologue: fill buffer 0, prefetch mask for k0=32
    stageB(0, 0);
    transform(0, 0, mk[mrow]);
    uint32_t mnext = mk[mrow + 1];
    __syncthreads();

    for (int k0 = 0; k0 < NN; k0 += 32) {
        const int p = (k0 >> 5) & 1;
        if (k0 + 32 < NN) {
            stageB(p ^ 1, k0 + 32);
            uint32_t mfar = 0;
            if (k0 + 64 < NN) mfar = mk[mrow + ((k0 + 64) >> 5)];
            transform(p ^ 1, k0 + 32, mnext);
            mnext = mfar;
        }
        short8 af[2], bf[8];
#pragma unroll
        for (int t = 0; t < 2; ++t) af[t] = *(const short8*)&As[p][(wi * 32 + t * 16) * 32 + fro];
#pragma unroll
        for (int t = 0; t < 8; ++t) bf[t] = *(const short8*)&Bs[p][(wj * 128 + t * 16) * 32 + fro];
#pragma unroll
        for (int it = 0; it < 2; ++it)
#pragma unroll
            for (int jt = 0; jt < 8; ++jt)
                acc[it][jt] = __builtin_amdgcn_mfma_f32_16x16x32_bf16(af[it], bf[jt], acc[it][jt], 0, 0, 0);
        if (wj == 0) {
#pragma unroll
            for (int it = 0; it < 2; ++it)
                acc_z[it] = __builtin_amdgcn_mfma_f32_16x16x32_bf16(af[it], ones, acc_z[it], 0, 0, 0);
        }
        __syncthreads();
    }

    // Z: wj==0 waves hold row sums in acc_z (all 16 cols identical)
    if (wj == 0 && (lane & 15) == 0) {
#pragma unroll
        for (int it = 0; it < 2; ++it) {
            const int rb = wi * 32 + it * 16 + ((lane >> 4) << 2);
#pragma unroll
            for (int r = 0; r < 4; ++r) rzl[rb + r] = 1.0f / acc_z[it][r];
        }
    }
    __syncthreads();

    // epilogue: scale by 1/Z, add residual, plain fp32 stores
#pragma unroll
    for (int it = 0; it < 2; ++it) {
        const int rb = wi * 32 + it * 16 + ((lane >> 4) << 2);
        float rv[4];
#pragma unroll
        for (int r = 0; r < 4; ++r) rv[r] = rzl[rb + r];
#pragma unroll
        for (int jt = 0; jt < 8; ++jt) {
            const int col = n0 + wj * 128 + jt * 16 + (lane & 15);
#pragma unroll
            for (int r = 0; r < 4; ++r) {
                const size_t idx = (rowbase + rb + r) * HH + col;
                out[idx] = acc[it][jt][r] * rv[r] + feats[idx];
            }
        }
    }
}

extern "C" void kernel_launch(void* const* d_in, const int* in_sizes, int n_in,
                              void* d_out, int out_size, void* d_ws, size_t ws_size,
                              hipStream_t stream) {
    const float* feats = (const float*)d_in[0];
    const float* adj   = (const float*)d_in[1];
    const float* fc_w  = (const float*)d_in[2];
    const float* fc_b  = (const float*)d_in[3];
    const float* q_w   = (const float*)d_in[4];
    const float* q_b   = (const float*)d_in[5];
    const float* k_w   = (const float*)d_in[6];
    const float* k_b   = (const float*)d_in[7];
    float* out = (float*)d_out;

    char* w = (char*)d_ws;
    auto alloc = [&](size_t bytes) {
        char* p = w;
        w += (bytes + 255) & ~(size_t)255;
        return p;
    };
    unsigned short* feats_bf = (unsigned short*)alloc((size_t)BSZ * NN * HH * 2); // 16.8 MB
    unsigned short* fcw_bf   = (unsigned short*)alloc((size_t)HH * HH * 2);       // 0.5 MB
    unsigned short* fpT   = (unsigned short*)alloc((size_t)BSZ * HH * NN * 2);    // 16.8 MB
    unsigned char*  maskb = (unsigned char*)alloc((size_t)MROWS * 256);           // 4.2 MB
    float* qpart = (float*)alloc((size_t)4 * MROWS * 4);                          // 256 KB
    float* kpart = (float*)alloc((size_t)4 * MROWS * 4);                          // 256 KB

    prep_kernel<<<2112, 256, 0, stream>>>(feats, fc_w, feats_bf, fcw_bf);
    k2_kernel<<<512 + 2048, 256, 0, stream>>>(feats_bf, fcw_bf, fc_b, q_w, k_w, adj,
                                              fpT, maskb, qpart, kpart);
    fused_pv_kernel<<<512, 256, 0, stream>>>(
        fpT, maskb, qpart, kpart, q_b, k_b, feats, out);
}